// Round 4
// baseline (1401.433 us; speedup 1.0000x reference)
//
#include <hip/hip_runtime.h>
#include <math.h>

typedef _Float16 half8 __attribute__((ext_vector_type(8)));
typedef float float4v __attribute__((ext_vector_type(4)));

constexpr int Lc   = 2048;  // L_IN
constexpr int DECc = 64;    // DEC_LEN
constexpr int Hc   = 128;   // H
constexpr int EMBc = 16;    // EMB
constexpr int INc  = 18;    // IN_SIZE
constexpr int NBc  = 4;     // batches per block
constexpr int NTc  = 512;   // 8 waves
constexpr int CARD = 200;
constexpr int ZS   = 160;   // z stride per batch (halves); 320B keeps b128 reads 2-way (free)

// z holds ONLY h (k=0..127). The x-part (K-slot 4, k=128..159 -> Wih cols 0..17) is an
// A-fragment built in REGISTERS (ax), prefetched during the previous step from
// [t][b]-interleaved static tables (broadcast reads, full-step slack, no writer role).
// Chain per gate: mfma(ax, Bf[4], bias) first (register operands -- issues before Az
// loads return), then 4 chained h-MFMAs. Decoder: mu fed back as rank-1 w17 term.

__device__ __forceinline__ float rcp_(float x) { return __builtin_amdgcn_rcpf(x); }
__device__ __forceinline__ float sigm(float x) { return rcp_(1.0f + __expf(-x)); }
__device__ __forceinline__ float tanh_(float x) { return 2.0f * rcp_(1.0f + __expf(-2.0f * x)) - 1.0f; }
__device__ __forceinline__ float softplus_(float x) { return __logf(1.0f + __expf(x)); }

// dynamic 4-element select (3 cndmask)
__device__ __forceinline__ float sel4(float4v v, int q) {
    const float a = (q & 1) ? v[1] : v[0];
    const float b = (q & 1) ? v[3] : v[2];
    return (q & 2) ? b : a;
}

__global__ __launch_bounds__(NTc, 1) void rnnar_kernel(
    const int*   __restrict__ cat_in,  const float* __restrict__ cont_in,
    const float* __restrict__ X_in,    const int*   __restrict__ cat_out,
    const float* __restrict__ cont_out,const float* __restrict__ emb_table,
    const float* __restrict__ cont_w,
    const float* __restrict__ Wih_e, const float* __restrict__ Whh_e, const float* __restrict__ b_e,
    const float* __restrict__ Wih_d, const float* __restrict__ Whh_d, const float* __restrict__ b_d,
    const float* __restrict__ Wm, const float* __restrict__ bm,
    const float* __restrict__ Ws, const float* __restrict__ bs,
    const float* __restrict__ Wv, const float* __restrict__ bv,
    float* __restrict__ out)
{
    __shared__ _Float16      z_lds[2][NBc * ZS];     // 2.5 KB double-buffered h
    __shared__ _Float16      emb_lds[CARD * EMBc];   // 6.4 KB
    __shared__ _Float16      xs04[Lc * NBc];         // 16 KB [t][b] cont_in*w00
    __shared__ _Float16      xs14[Lc * NBc];         // 16 KB [t][b] X_in
    __shared__ unsigned char catb4[Lc * NBc];        // 8 KB  [t][b]
    __shared__ _Float16      xo4[DECc * NBc];        // 512 B [t][b] cont_out*w00
    __shared__ unsigned char catob4[DECc * NBc];     // 256 B [t][b]
    __shared__ float         h32_lds[NBc * 132];     // 2.1 KB
    __shared__ float         wh_lds[6 * Hc];         // 3 KB
    __shared__ float         hb_lds[8];
    __shared__ float         mu_lds[4];

    const int tid  = threadIdx.x;
    const int lane = tid & 63;
    const int wv   = tid >> 6;        // wave 0..7
    const int q    = lane >> 4;       // quad 0..3 = this lane's batch (activations)
    const int col  = lane & 15;       // cell-local 0..15
    const int cell = 16 * wv + col;   // this lane's cell
    const int bx   = col & 3;         // A-frag batch
    const int b0   = blockIdx.x * NBc;
    const float w00 = cont_w[0];

    // ---------------- staging ----------------
    {
        int* z32 = (int*)&z_lds[0][0];
        for (int i = tid; i < NBc * ZS; i += NTc) z32[i] = 0;  // both buffers (2*NBc*ZS halves)
    }
    for (int i = tid; i < CARD * EMBc; i += NTc) emb_lds[i] = (_Float16)emb_table[i];
    for (int i = tid; i < Lc * NBc; i += NTc) {     // [t][b] interleave -> broadcast reads
        const int t = i >> 2, b = i & 3;
        catb4[i] = (unsigned char)cat_in[(b0 + b) * Lc + t];
        xs04[i]  = (_Float16)(cont_in[(b0 + b) * Lc + t] * w00);
        xs14[i]  = (_Float16)(X_in[(b0 + b) * Lc + t]);
    }
    if (tid < NBc * DECc) {
        const int t = tid >> 2, b = tid & 3;
        catob4[tid] = (unsigned char)cat_out[(b0 + b) * DECc + t];
        xo4[tid]    = (_Float16)(cont_out[(b0 + b) * DECc + t] * w00);
    }
    for (int i = tid; i < 6 * Hc; i += NTc) {
        const int o = i >> 7, k = i & 127;
        wh_lds[i] = (o == 0) ? Wm[k] : (o == 1) ? Ws[k] : Wv[(o - 2) * Hc + k];
    }
    if (tid == 0) { hb_lds[0] = bm[0]; hb_lds[1] = bs[0]; }
    if (tid < 4)  { hb_lds[2 + tid] = bv[tid]; mu_lds[tid] = 0.0f; }

    // ---- B-fragments: acc tile index == gate type; h-first K order ----
    half8 Bf[4][5];
    float bias_s[4];
    float w17_s[4];   // Wih[row][17] -- decoder mu rank-1 column
    #define LOAD_T(WIH, WHH, BB)                                               \
    {                                                                          \
        _Pragma("unroll")                                                      \
        for (int gt = 0; gt < 4; ++gt) {                                       \
            const int row = gt * Hc + cell;                                    \
            _Pragma("unroll")                                                  \
            for (int kt = 0; kt < 5; ++kt) {                                   \
                half8 f;                                                       \
                _Pragma("unroll")                                              \
                for (int j = 0; j < 8; ++j) {                                  \
                    const int k = 32 * kt + 8 * q + j;                         \
                    float v = 0.0f;                                            \
                    if (k < Hc)             v = WHH[row * Hc + k];             \
                    else if (k < Hc + INc)  v = WIH[row * INc + (k - Hc)];     \
                    f[j] = (_Float16)v;                                        \
                }                                                              \
                Bf[gt][kt] = f;                                                \
            }                                                                  \
            bias_s[gt] = BB[row];                                              \
            w17_s[gt]  = WIH[row * INc + 17];                                  \
        }                                                                      \
    }

    LOAD_T(Wih_e, Whh_e, b_e);
    float4v bias4[4];
    #pragma unroll
    for (int gt = 0; gt < 4; ++gt)
        bias4[gt] = (float4v){bias_s[gt], bias_s[gt], bias_s[gt], bias_s[gt]};
    __syncthreads();

    // prologue: ax(0) from static tables
    half8 ax;
    #pragma unroll
    for (int j = 0; j < 8; ++j) ax[j] = (_Float16)0.0f;
    if (q < 2) {
        const int c4 = (int)catb4[0 * 4 + bx];
        ax = *(const half8*)&emb_lds[c4 * EMBc + 8 * q];
    } else if (q == 2) {
        ax[0] = xs04[bx];
        ax[1] = xs14[bx];
    }

    int p = 0;
    float c_reg = 0.f;

    // ===================== encoder: 1 barrier/step, no global ops in loop =====================
    for (int t = 0; t < Lc; ++t) {
        const _Float16* zr = &z_lds[p][0];
        _Float16*       zw = &z_lds[p ^ 1][0];

        // h A-frags (k-tiles 0..3)
        const _Float16* ap = zr + bx * ZS + 8 * q;
        half8 Az[4];
        #pragma unroll
        for (int kt = 0; kt < 4; ++kt) Az[kt] = *(const half8*)(ap + 32 * kt);

        float4v acc[4];
        #pragma unroll
        for (int gt = 0; gt < 4; ++gt) {
            // ax-MFMA first: register operands, issues before Az loads return
            float4v a = __builtin_amdgcn_mfma_f32_16x16x32_f16(ax, Bf[gt][4], bias4[gt], 0, 0, 0);
            #pragma unroll
            for (int kt = 0; kt < 4; ++kt)
                a = __builtin_amdgcn_mfma_f32_16x16x32_f16(Az[kt], Bf[gt][kt], a, 0, 0, 0);
            acc[gt] = a;
        }

        // prefetch ax(t+1) with full-step slack (static tables, broadcast reads)
        // t = Lc-1 clamps -> x(Lc-1), which IS the decoder's x(0).
        const int tn = (t + 1 < Lc) ? t + 1 : Lc - 1;
        half8 axn;
        #pragma unroll
        for (int j = 0; j < 8; ++j) axn[j] = (_Float16)0.0f;
        if (q < 2) {
            const int c4 = (int)catb4[tn * 4 + bx];
            axn = *(const half8*)&emb_lds[c4 * EMBc + 8 * q];
        } else if (q == 2) {
            axn[0] = xs04[tn * 4 + bx];
            axn[1] = xs14[tn * 4 + bx];
        }

        // gates land in-lane: batch q, cell = 16wv+col
        const float gi = sel4(acc[0], q);
        const float gf = sel4(acc[1], q);
        const float gg = sel4(acc[2], q);
        const float go = sel4(acc[3], q);

        const float cn = sigm(gf) * c_reg + sigm(gi) * tanh_(gg);
        c_reg = cn;
        zw[q * ZS + cell] = (_Float16)(sigm(go) * tanh_(cn));

        ax = axn;
        __syncthreads();
        p ^= 1;
    }

    // ===================== decoder =====================
    LOAD_T(Wih_d, Whh_d, b_d);
    #pragma unroll
    for (int gt = 0; gt < 4; ++gt)
        bias4[gt] = (float4v){bias_s[gt], bias_s[gt], bias_s[gt], bias_s[gt]};
    const float bm0 = hb_lds[0], bs0 = hb_lds[1];
    // ax currently = x(Lc-1) (incl. X_in[-1] in slot 17) = decoder x(0); mu_lds = 0.

    for (int t = 0; t < DECc; ++t) {
        const _Float16* zr = &z_lds[p][0];
        _Float16*       zw = &z_lds[p ^ 1][0];

        const float muq = mu_lds[q];   // mu(t-1) for this lane's batch (0 at t=0)

        const _Float16* ap = zr + bx * ZS + 8 * q;
        half8 Az[4];
        #pragma unroll
        for (int kt = 0; kt < 4; ++kt) Az[kt] = *(const half8*)(ap + 32 * kt);

        float4v acc[4];
        #pragma unroll
        for (int gt = 0; gt < 4; ++gt) {
            float4v a = __builtin_amdgcn_mfma_f32_16x16x32_f16(ax, Bf[gt][4], bias4[gt], 0, 0, 0);
            #pragma unroll
            for (int kt = 0; kt < 4; ++kt)
                a = __builtin_amdgcn_mfma_f32_16x16x32_f16(Az[kt], Bf[gt][kt], a, 0, 0, 0);
            acc[gt] = a;
        }

        // prefetch ax(t+1) = [emb(cat_out t), cont_out t, mu-slot 0] (mu via w17 next step)
        half8 axn;
        #pragma unroll
        for (int j = 0; j < 8; ++j) axn[j] = (_Float16)0.0f;
        if (q < 2) {
            const int c4 = (int)catob4[t * 4 + bx];
            axn = *(const half8*)&emb_lds[c4 * EMBc + 8 * q];
        } else if (q == 2) {
            axn[0] = xo4[t * 4 + bx];
        }

        // gates with mu rank-1 correction
        const float gi = sel4(acc[0], q) + muq * w17_s[0];
        const float gf = sel4(acc[1], q) + muq * w17_s[1];
        const float gg = sel4(acc[2], q) + muq * w17_s[2];
        const float go = sel4(acc[3], q) + muq * w17_s[3];

        const float cn = sigm(gf) * c_reg + sigm(gi) * tanh_(gg);
        c_reg = cn;
        const float hv = sigm(go) * tanh_(cn);
        zw[q * ZS + cell] = (_Float16)hv;
        h32_lds[q * 132 + cell] = hv;

        ax = axn;
        __syncthreads();

        // heads: 24 dot-products x 16 lanes each (8 strided FMAs + shfl reduce)
        if (tid < 384) {
            const int grp = tid >> 4;       // 0..23, wave-aligned 16-thread groups
            const int l16 = tid & 15;
            const int b   = grp & 3, o = grp >> 2;  // o = 0..5
            float s = 0.0f;
            #pragma unroll
            for (int j = 0; j < 8; ++j) {
                const int k = l16 + 16 * j;
                s += wh_lds[o * Hc + k] * h32_lds[b * 132 + k];
            }
            s += __shfl_xor(s, 1);
            s += __shfl_xor(s, 2);
            s += __shfl_xor(s, 4);
            s += __shfl_xor(s, 8);
            if (l16 == 0) {
                const int gb2 = b0 + b;
                if (o == 0) {
                    const float mu = s + bm0;
                    out[gb2 * DECc + t] = mu;
                    mu_lds[b] = mu;   // feedback for rank-1 correction next step
                } else if (o == 1) {
                    out[65536 + gb2 * DECc + t] = softplus_(s + bs0);
                } else {
                    out[131072 + (gb2 * DECc + t) * 4 + (o - 2)] = s + hb_lds[2 + (o - 2)];
                }
            }
        }
        __syncthreads();
        p ^= 1;
    }
    #undef LOAD_T
}

extern "C" void kernel_launch(void* const* d_in, const int* in_sizes, int n_in,
                              void* d_out, int out_size, void* d_ws, size_t ws_size,
                              hipStream_t stream) {
    rnnar_kernel<<<1024 / NBc, NTc, 0, stream>>>(
        (const int*)d_in[0],   (const float*)d_in[1],  (const float*)d_in[2],
        (const int*)d_in[3],   (const float*)d_in[4],  (const float*)d_in[5],
        (const float*)d_in[6],
        (const float*)d_in[7], (const float*)d_in[8],  (const float*)d_in[9],
        (const float*)d_in[10],(const float*)d_in[11], (const float*)d_in[12],
        (const float*)d_in[13],(const float*)d_in[14],
        (const float*)d_in[15],(const float*)d_in[16],
        (const float*)d_in[17],(const float*)d_in[18],
        (float*)d_out);
}

// Round 5
// 1294.191 us; speedup vs baseline: 1.0829x; 1.0829x over previous
//
#include <hip/hip_runtime.h>
#include <math.h>

typedef _Float16 half8 __attribute__((ext_vector_type(8)));
typedef _Float16 half4 __attribute__((ext_vector_type(4)));
typedef float float4v __attribute__((ext_vector_type(4)));

constexpr int Lc   = 2048;  // L_IN
constexpr int DECc = 64;    // DEC_LEN
constexpr int Hc   = 128;   // H
constexpr int EMBc = 16;    // EMB
constexpr int INc  = 18;    // IN_SIZE
constexpr int NBc  = 4;     // batches per block
constexpr int NTc  = 512;   // 8 waves
constexpr int KT   = 5;     // k-tiles of 32 (z padded to 160)
constexpr int CARD = 200;
constexpr int ZS   = 160;   // z stride per batch (halves); 320B -> 2-way (free) on b128 reads

// R1 structure (proven best): z = [x(18) | h(128) | pad], staged in LDS, 5 uniform
// k-tiles, gate-type-per-accumulator (gates land in-lane, no shuffle).
// R5 changes: (a) x-writer block HOISTED to loop top so its cat->emb->write chain
// overlaps the MFMA phase instead of extending the pre-barrier tail;
// (b) [t][b]-interleaved static tables (conflict-free writer reads).

__device__ __forceinline__ float rcp_(float x) { return __builtin_amdgcn_rcpf(x); }
__device__ __forceinline__ float sigm(float x) { return rcp_(1.0f + __expf(-x)); }
__device__ __forceinline__ float tanh_(float x) { return 2.0f * rcp_(1.0f + __expf(-2.0f * x)) - 1.0f; }
__device__ __forceinline__ float softplus_(float x) { return __logf(1.0f + __expf(x)); }

// dynamic 4-element select (3 cndmask)
__device__ __forceinline__ float sel4(float4v v, int q) {
    const float a = (q & 1) ? v[1] : v[0];
    const float b = (q & 1) ? v[3] : v[2];
    return (q & 2) ? b : a;
}

__global__ __launch_bounds__(NTc, 1) void rnnar_kernel(
    const int*   __restrict__ cat_in,  const float* __restrict__ cont_in,
    const float* __restrict__ X_in,    const int*   __restrict__ cat_out,
    const float* __restrict__ cont_out,const float* __restrict__ emb_table,
    const float* __restrict__ cont_w,
    const float* __restrict__ Wih_e, const float* __restrict__ Whh_e, const float* __restrict__ b_e,
    const float* __restrict__ Wih_d, const float* __restrict__ Whh_d, const float* __restrict__ b_d,
    const float* __restrict__ Wm, const float* __restrict__ bm,
    const float* __restrict__ Ws, const float* __restrict__ bs,
    const float* __restrict__ Wv, const float* __restrict__ bv,
    float* __restrict__ out)
{
    __shared__ _Float16      z_lds[2][NBc * ZS];     // 2.5 KB double-buffered z, [b][k]
    __shared__ _Float16      emb_lds[CARD * EMBc];   // 6.4 KB
    __shared__ _Float16      xs04[Lc * NBc];         // 16 KB [t][b] cont_in * w00
    __shared__ _Float16      xs14[Lc * NBc];         // 16 KB [t][b] X_in
    __shared__ unsigned char catb4[Lc * NBc];        // 8 KB  [t][b]
    __shared__ _Float16      xo4[DECc * NBc];        // 512 B [t][b] cont_out * w00
    __shared__ unsigned char catob4[DECc * NBc];     // 256 B [t][b]
    __shared__ float         h32_lds[NBc * 132];     // 2.1 KB
    __shared__ float         wh_lds[6 * Hc];         // 3 KB
    __shared__ float         hb_lds[8];

    const int tid  = threadIdx.x;
    const int lane = tid & 63;
    const int wv   = tid >> 6;        // wave 0..7
    const int q    = lane >> 4;       // quad 0..3 = this lane's batch (activations)
    const int col  = lane & 15;       // cell-local 0..15
    const int cell = 16 * wv + col;   // this lane's cell
    const int bx   = col & 3;         // A-frag batch
    const int b0   = blockIdx.x * NBc;
    const float w00 = cont_w[0];

    const int xk = tid >> 2, xb = tid & 3;   // x-writer role (tid < 72)

    // ---------------- staging ----------------
    {
        int* z32 = (int*)&z_lds[0][0];
        for (int i = tid; i < NBc * ZS; i += NTc) z32[i] = 0;  // both buffers
    }
    for (int i = tid; i < CARD * EMBc; i += NTc) emb_lds[i] = (_Float16)emb_table[i];
    for (int i = tid; i < Lc * NBc; i += NTc) {     // [t][b] interleave
        const int t = i >> 2, b = i & 3;
        catb4[i] = (unsigned char)cat_in[(b0 + b) * Lc + t];
        xs04[i]  = (_Float16)(cont_in[(b0 + b) * Lc + t] * w00);
        xs14[i]  = (_Float16)(X_in[(b0 + b) * Lc + t]);
    }
    if (tid < NBc * DECc) {
        const int t = tid >> 2, b = tid & 3;
        catob4[tid] = (unsigned char)cat_out[(b0 + b) * DECc + t];
        xo4[tid]    = (_Float16)(cont_out[(b0 + b) * DECc + t] * w00);
    }
    for (int i = tid; i < 6 * Hc; i += NTc) {
        const int o = i >> 7, k = i & 127;
        wh_lds[i] = (o == 0) ? Wm[k] : (o == 1) ? Ws[k] : Wv[(o - 2) * Hc + k];
    }
    if (tid == 0) { hb_lds[0] = bm[0]; hb_lds[1] = bs[0]; }
    if (tid < 4)  { hb_lds[2 + tid] = bv[tid]; }

    // ---- B-fragments: acc tile index == gate type; x-first K order (R1 layout) ----
    half8 Bf[4][KT];
    float bias_s[4];
    #define LOAD_T(WIH, WHH, BB)                                               \
    {                                                                          \
        _Pragma("unroll")                                                      \
        for (int gt = 0; gt < 4; ++gt) {                                       \
            const int row = gt * Hc + cell;                                    \
            _Pragma("unroll")                                                  \
            for (int kt = 0; kt < KT; ++kt) {                                  \
                half8 f;                                                       \
                _Pragma("unroll")                                              \
                for (int j = 0; j < 8; ++j) {                                  \
                    const int k = 32 * kt + 8 * q + j;                         \
                    float v = 0.0f;                                            \
                    if (k < INc)            v = WIH[row * INc + k];            \
                    else if (k < INc + Hc)  v = WHH[row * Hc + (k - INc)];     \
                    f[j] = (_Float16)v;                                        \
                }                                                              \
                Bf[gt][kt] = f;                                                \
            }                                                                  \
            bias_s[gt] = BB[row];                                              \
        }                                                                      \
    }

    LOAD_T(Wih_e, Whh_e, b_e);
    float4v bias4[4];
    #pragma unroll
    for (int gt = 0; gt < 4; ++gt)
        bias4[gt] = (float4v){bias_s[gt], bias_s[gt], bias_s[gt], bias_s[gt]};
    __syncthreads();

    // x(0) into buffer 0
    if (tid < INc * NBc) {
        _Float16 v;
        if (xk < EMBc)       v = emb_lds[(int)catb4[0 * 4 + xb] * EMBc + xk];
        else if (xk == EMBc) v = xs04[0 * 4 + xb];
        else                 v = xs14[0 * 4 + xb];
        z_lds[0][xb * ZS + xk] = v;
    }
    __syncthreads();

    int p = 0;
    float c_reg = 0.f;

    // ===================== encoder: 1 barrier/step =====================
    for (int t = 0; t < Lc; ++t) {
        const _Float16* zr = &z_lds[p][0];
        _Float16*       zw = &z_lds[p ^ 1][0];

        // HOISTED x-writer: x(t+1) -> zw, issued before everything else so the
        // cat->emb->write chain overlaps the MFMA phase. zw is the write buffer;
        // no one reads it until after the barrier. t=Lc-1 clamps -> decoder x(0).
        if (tid < INc * NBc) {
            const int t1 = (t + 1 < Lc) ? t + 1 : Lc - 1;
            _Float16 v;
            if (xk < EMBc)       v = emb_lds[(int)catb4[t1 * 4 + xb] * EMBc + xk];
            else if (xk == EMBc) v = xs04[t1 * 4 + xb];
            else                 v = xs14[t1 * 4 + xb];
            zw[xb * ZS + xk] = v;
        }

        // A-frags from z (batch = col&3)
        const _Float16* ap = zr + bx * ZS + 8 * q;
        half8 Az[KT];
        #pragma unroll
        for (int kt = 0; kt < KT; ++kt) Az[kt] = *(const half8*)(ap + 32 * kt);

        float4v acc[4];
        #pragma unroll
        for (int gt = 0; gt < 4; ++gt) {
            float4v a = bias4[gt];
            #pragma unroll
            for (int kt = 0; kt < KT; ++kt)
                a = __builtin_amdgcn_mfma_f32_16x16x32_f16(Az[kt], Bf[gt][kt], a, 0, 0, 0);
            acc[gt] = a;
        }

        // gates land in-lane: batch q, cell = 16wv+col
        const float gi = sel4(acc[0], q);
        const float gf = sel4(acc[1], q);
        const float gg = sel4(acc[2], q);
        const float go = sel4(acc[3], q);

        const float cn = sigm(gf) * c_reg + sigm(gi) * tanh_(gg);
        c_reg = cn;
        zw[q * ZS + INc + cell] = (_Float16)(sigm(go) * tanh_(cn));

        __syncthreads();
        p ^= 1;
    }

    // ===================== decoder =====================
    LOAD_T(Wih_d, Whh_d, b_d);
    #pragma unroll
    for (int gt = 0; gt < 4; ++gt)
        bias4[gt] = (float4v){bias_s[gt], bias_s[gt], bias_s[gt], bias_s[gt]};
    const float bm0 = hb_lds[0], bs0 = hb_lds[1];

    for (int t = 0; t < DECc; ++t) {
        const _Float16* zr = &z_lds[p][0];
        _Float16*       zw = &z_lds[p ^ 1][0];

        // HOISTED x-writer: feats_out(t) -> x(t+1) slots 0..16; slot 17 (mu) by heads
        if (tid < INc * NBc && xk < INc - 1) {
            _Float16 v;
            if (xk < EMBc) v = emb_lds[(int)catob4[t * 4 + xb] * EMBc + xk];
            else           v = xo4[t * 4 + xb];
            zw[xb * ZS + xk] = v;
        }

        const _Float16* ap = zr + bx * ZS + 8 * q;
        half8 Az[KT];
        #pragma unroll
        for (int kt = 0; kt < KT; ++kt) Az[kt] = *(const half8*)(ap + 32 * kt);

        float4v acc[4];
        #pragma unroll
        for (int gt = 0; gt < 4; ++gt) {
            float4v a = bias4[gt];
            #pragma unroll
            for (int kt = 0; kt < KT; ++kt)
                a = __builtin_amdgcn_mfma_f32_16x16x32_f16(Az[kt], Bf[gt][kt], a, 0, 0, 0);
            acc[gt] = a;
        }

        const float gi = sel4(acc[0], q);
        const float gf = sel4(acc[1], q);
        const float gg = sel4(acc[2], q);
        const float go = sel4(acc[3], q);

        const float cn = sigm(gf) * c_reg + sigm(gi) * tanh_(gg);
        c_reg = cn;
        const float hv = sigm(go) * tanh_(cn);
        zw[q * ZS + INc + cell] = (_Float16)hv;
        h32_lds[q * 132 + cell] = hv;

        __syncthreads();

        // heads: 24 dot-products x 16 lanes each (8 strided FMAs + shfl reduce)
        if (tid < 384) {
            const int grp = tid >> 4;       // 0..23, wave-aligned 16-thread groups
            const int l16 = tid & 15;
            const int b   = grp & 3, o = grp >> 2;  // o = 0..5
            float s = 0.0f;
            #pragma unroll
            for (int j = 0; j < 8; ++j) {
                const int k = l16 + 16 * j;
                s += wh_lds[o * Hc + k] * h32_lds[b * 132 + k];
            }
            s += __shfl_xor(s, 1);
            s += __shfl_xor(s, 2);
            s += __shfl_xor(s, 4);
            s += __shfl_xor(s, 8);
            if (l16 == 0) {
                const int gb = b0 + b;
                if (o == 0) {
                    const float mu = s + bm0;
                    out[gb * DECc + t] = mu;
                    zw[b * ZS + (INc - 1)] = (_Float16)mu;   // mu feedback into x slot 17
                } else if (o == 1) {
                    out[65536 + gb * DECc + t] = softplus_(s + bs0);
                } else {
                    out[131072 + (gb * DECc + t) * 4 + (o - 2)] = s + hb_lds[2 + (o - 2)];
                }
            }
        }
        __syncthreads();
        p ^= 1;
    }
    #undef LOAD_T
}

extern "C" void kernel_launch(void* const* d_in, const int* in_sizes, int n_in,
                              void* d_out, int out_size, void* d_ws, size_t ws_size,
                              hipStream_t stream) {
    rnnar_kernel<<<1024 / NBc, NTc, 0, stream>>>(
        (const int*)d_in[0],   (const float*)d_in[1],  (const float*)d_in[2],
        (const int*)d_in[3],   (const float*)d_in[4],  (const float*)d_in[5],
        (const float*)d_in[6],
        (const float*)d_in[7], (const float*)d_in[8],  (const float*)d_in[9],
        (const float*)d_in[10],(const float*)d_in[11], (const float*)d_in[12],
        (const float*)d_in[13],(const float*)d_in[14],
        (const float*)d_in[15],(const float*)d_in[16],
        (const float*)d_in[17],(const float*)d_in[18],
        (float*)d_out);
}

// Round 6
// 1268.542 us; speedup vs baseline: 1.1048x; 1.0202x over previous
//
#include <hip/hip_runtime.h>
#include <math.h>

typedef _Float16 half8 __attribute__((ext_vector_type(8)));
typedef _Float16 half2v __attribute__((ext_vector_type(2)));
typedef float float4v __attribute__((ext_vector_type(4)));

constexpr int Lc   = 2048;  // L_IN
constexpr int DECc = 64;    // DEC_LEN
constexpr int Hc   = 128;   // H
constexpr int EMBc = 16;    // EMB
constexpr int INc  = 18;    // IN_SIZE
constexpr int NBc  = 4;     // batches per block
constexpr int NTc  = 512;   // 8 waves
constexpr int KT   = 5;     // k-tiles of 32 (z padded to 160)
constexpr int CARD = 200;
constexpr int ZS   = 160;   // z stride per batch (halves); 320B -> 2-way (free) on b128 reads

// R1 structure (proven best): z = [x(18) | h(128) | pad], double-buffered in LDS,
// 5 uniform k-tiles, gate-type-per-accumulator (gates land in-lane, no shuffle).
// R6 surgical edits vs R1: (a) cat index for the x-writer prefetched at loop top
// (breaks the byte-read -> emb-gather dependence; index arrives during the MFMA
// window); (b) writer vectorized to 16 lanes (2x ds_read_b128 + b128 writes,
// 2-way-free banks) instead of 72 scalar b16 ops; (c) [t][b]-interleaved static
// tables. Writer POSITION kept at loop bottom exactly as R1 (R5's hoist spilled).

__device__ __forceinline__ float rcp_(float x) { return __builtin_amdgcn_rcpf(x); }
__device__ __forceinline__ float sigm(float x) { return rcp_(1.0f + __expf(-x)); }
__device__ __forceinline__ float tanh_(float x) { return 2.0f * rcp_(1.0f + __expf(-2.0f * x)) - 1.0f; }
__device__ __forceinline__ float softplus_(float x) { return __logf(1.0f + __expf(x)); }

// dynamic 4-element select (3 cndmask)
__device__ __forceinline__ float sel4(float4v v, int q) {
    const float a = (q & 1) ? v[1] : v[0];
    const float b = (q & 1) ? v[3] : v[2];
    return (q & 2) ? b : a;
}

__global__ __launch_bounds__(NTc, 1) void rnnar_kernel(
    const int*   __restrict__ cat_in,  const float* __restrict__ cont_in,
    const float* __restrict__ X_in,    const int*   __restrict__ cat_out,
    const float* __restrict__ cont_out,const float* __restrict__ emb_table,
    const float* __restrict__ cont_w,
    const float* __restrict__ Wih_e, const float* __restrict__ Whh_e, const float* __restrict__ b_e,
    const float* __restrict__ Wih_d, const float* __restrict__ Whh_d, const float* __restrict__ b_d,
    const float* __restrict__ Wm, const float* __restrict__ bm,
    const float* __restrict__ Ws, const float* __restrict__ bs,
    const float* __restrict__ Wv, const float* __restrict__ bv,
    float* __restrict__ out)
{
    __shared__ _Float16      z_lds[2][NBc * ZS];     // 2.5 KB double-buffered z, [b][k]
    __shared__ _Float16      emb_lds[CARD * EMBc];   // 6.4 KB (rows 32B-aligned for b128)
    __shared__ _Float16      xs04[Lc * NBc];         // 16 KB [t][b] cont_in * w00
    __shared__ _Float16      xs14[Lc * NBc];         // 16 KB [t][b] X_in
    __shared__ unsigned char catb4[Lc * NBc];        // 8 KB  [t][b]
    __shared__ _Float16      xo4[DECc * NBc];        // 512 B [t][b] cont_out * w00
    __shared__ unsigned char catob4[DECc * NBc];     // 256 B [t][b]
    __shared__ float         h32_lds[NBc * 132];     // 2.1 KB
    __shared__ float         wh_lds[6 * Hc];         // 3 KB
    __shared__ float         hb_lds[8];

    const int tid  = threadIdx.x;
    const int lane = tid & 63;
    const int wv   = tid >> 6;        // wave 0..7
    const int q    = lane >> 4;       // quad 0..3 = this lane's batch (activations)
    const int col  = lane & 15;       // cell-local 0..15
    const int cell = 16 * wv + col;   // this lane's cell
    const int bx   = col & 3;         // A-frag batch
    const int b0   = blockIdx.x * NBc;
    const float w00 = cont_w[0];

    const int wsub = tid & 3;         // x-writer role within batch (tid < 16)
    const int wxb  = tid >> 2;        // x-writer batch 0..3

    // ---------------- staging ----------------
    {
        int* z32 = (int*)&z_lds[0][0];
        for (int i = tid; i < NBc * ZS; i += NTc) z32[i] = 0;  // both buffers
    }
    for (int i = tid; i < CARD * EMBc; i += NTc) emb_lds[i] = (_Float16)emb_table[i];
    for (int i = tid; i < Lc * NBc; i += NTc) {     // coalesced global reads, [t][b] LDS
        const int b = i >> 11, t = i & (Lc - 1);
        catb4[t * 4 + b] = (unsigned char)cat_in[(b0 + b) * Lc + t];
        xs04[t * 4 + b]  = (_Float16)(cont_in[(b0 + b) * Lc + t] * w00);
        xs14[t * 4 + b]  = (_Float16)(X_in[(b0 + b) * Lc + t]);
    }
    if (tid < NBc * DECc) {
        const int b = tid >> 6, t = tid & 63;
        catob4[t * 4 + b] = (unsigned char)cat_out[(b0 + b) * DECc + t];
        xo4[t * 4 + b]    = (_Float16)(cont_out[(b0 + b) * DECc + t] * w00);
    }
    for (int i = tid; i < 6 * Hc; i += NTc) {
        const int o = i >> 7, k = i & 127;
        wh_lds[i] = (o == 0) ? Wm[k] : (o == 1) ? Ws[k] : Wv[(o - 2) * Hc + k];
    }
    if (tid == 0) { hb_lds[0] = bm[0]; hb_lds[1] = bs[0]; }
    if (tid < 4)  { hb_lds[2 + tid] = bv[tid]; }

    // ---- B-fragments: acc tile index == gate type; x-first K order (R1 layout) ----
    half8 Bf[4][KT];
    float bias_s[4];
    #define LOAD_T(WIH, WHH, BB)                                               \
    {                                                                          \
        _Pragma("unroll")                                                      \
        for (int gt = 0; gt < 4; ++gt) {                                       \
            const int row = gt * Hc + cell;                                    \
            _Pragma("unroll")                                                  \
            for (int kt = 0; kt < KT; ++kt) {                                  \
                half8 f;                                                       \
                _Pragma("unroll")                                              \
                for (int j = 0; j < 8; ++j) {                                  \
                    const int k = 32 * kt + 8 * q + j;                         \
                    float v = 0.0f;                                            \
                    if (k < INc)            v = WIH[row * INc + k];            \
                    else if (k < INc + Hc)  v = WHH[row * Hc + (k - INc)];     \
                    f[j] = (_Float16)v;                                        \
                }                                                              \
                Bf[gt][kt] = f;                                                \
            }                                                                  \
            bias_s[gt] = BB[row];                                              \
        }                                                                      \
    }

    LOAD_T(Wih_e, Whh_e, b_e);
    float4v bias4[4];
    #pragma unroll
    for (int gt = 0; gt < 4; ++gt)
        bias4[gt] = (float4v){bias_s[gt], bias_s[gt], bias_s[gt], bias_s[gt]};
    __syncthreads();

    // x(0) into buffer 0 (vectorized writer, same roles as the in-loop writer)
    if (tid < 16) {
        if (wsub < 2) {
            const int c4 = (int)catb4[0 * 4 + wxb];
            const half8 e8 = *(const half8*)&emb_lds[c4 * EMBc + 8 * wsub];
            *(half8*)(&z_lds[0][0] + wxb * ZS + 8 * wsub) = e8;
        } else if (wsub == 2) {
            half2v two; two[0] = xs04[0 * 4 + wxb]; two[1] = xs14[0 * 4 + wxb];
            *(half2v*)(&z_lds[0][0] + wxb * ZS + 16) = two;
        }
    }
    __syncthreads();

    int p = 0;
    float c_reg = 0.f;

    // ===================== encoder: 1 barrier/step =====================
    for (int t = 0; t < Lc; ++t) {
        const _Float16* zr = &z_lds[p][0];
        _Float16*       zw = &z_lds[p ^ 1][0];
        const int t1 = (t + 1 < Lc) ? t + 1 : Lc - 1;   // clamp: last write = decoder x(0)

        // prefetch x-writer's cat index (breaks the byte-read -> emb-gather chain;
        // has the whole MFMA window to complete)
        int c4n = 0;
        if (tid < 16 && wsub < 2) c4n = (int)catb4[t1 * 4 + wxb];

        // A-frags from z (batch = col&3)
        const _Float16* ap = zr + bx * ZS + 8 * q;
        half8 Az[KT];
        #pragma unroll
        for (int kt = 0; kt < KT; ++kt) Az[kt] = *(const half8*)(ap + 32 * kt);

        float4v acc[4];
        #pragma unroll
        for (int gt = 0; gt < 4; ++gt) {
            float4v a = bias4[gt];
            #pragma unroll
            for (int kt = 0; kt < KT; ++kt)
                a = __builtin_amdgcn_mfma_f32_16x16x32_f16(Az[kt], Bf[gt][kt], a, 0, 0, 0);
            acc[gt] = a;
        }

        // gates land in-lane: batch q, cell = 16wv+col
        const float gi = sel4(acc[0], q);
        const float gf = sel4(acc[1], q);
        const float gg = sel4(acc[2], q);
        const float go = sel4(acc[3], q);

        const float cn = sigm(gf) * c_reg + sigm(gi) * tanh_(gg);
        c_reg = cn;
        zw[q * ZS + INc + cell] = (_Float16)(sigm(go) * tanh_(cn));

        // x-writer (R1 position, vectorized): x(t+1) -> zw slots 0..17
        if (tid < 16) {
            if (wsub < 2) {
                const half8 e8 = *(const half8*)&emb_lds[c4n * EMBc + 8 * wsub];
                *(half8*)(zw + wxb * ZS + 8 * wsub) = e8;
            } else if (wsub == 2) {
                half2v two; two[0] = xs04[t1 * 4 + wxb]; two[1] = xs14[t1 * 4 + wxb];
                *(half2v*)(zw + wxb * ZS + 16) = two;
            }
        }

        __syncthreads();
        p ^= 1;
    }

    // ===================== decoder =====================
    LOAD_T(Wih_d, Whh_d, b_d);
    #pragma unroll
    for (int gt = 0; gt < 4; ++gt)
        bias4[gt] = (float4v){bias_s[gt], bias_s[gt], bias_s[gt], bias_s[gt]};
    const float bm0 = hb_lds[0], bs0 = hb_lds[1];

    for (int t = 0; t < DECc; ++t) {
        const _Float16* zr = &z_lds[p][0];
        _Float16*       zw = &z_lds[p ^ 1][0];

        // prefetch writer's cat index
        int c4n = 0;
        if (tid < 16 && wsub < 2) c4n = (int)catob4[t * 4 + wxb];

        const _Float16* ap = zr + bx * ZS + 8 * q;
        half8 Az[KT];
        #pragma unroll
        for (int kt = 0; kt < KT; ++kt) Az[kt] = *(const half8*)(ap + 32 * kt);

        float4v acc[4];
        #pragma unroll
        for (int gt = 0; gt < 4; ++gt) {
            float4v a = bias4[gt];
            #pragma unroll
            for (int kt = 0; kt < KT; ++kt)
                a = __builtin_amdgcn_mfma_f32_16x16x32_f16(Az[kt], Bf[gt][kt], a, 0, 0, 0);
            acc[gt] = a;
        }

        const float gi = sel4(acc[0], q);
        const float gf = sel4(acc[1], q);
        const float gg = sel4(acc[2], q);
        const float go = sel4(acc[3], q);

        const float cn = sigm(gf) * c_reg + sigm(gi) * tanh_(gg);
        c_reg = cn;
        const float hv = sigm(go) * tanh_(cn);
        zw[q * ZS + INc + cell] = (_Float16)hv;
        h32_lds[q * 132 + cell] = hv;

        // x-writer: feats_out(t) -> x(t+1) slots 0..16; slot 17 (mu) by heads
        if (tid < 16) {
            if (wsub < 2) {
                const half8 e8 = *(const half8*)&emb_lds[c4n * EMBc + 8 * wsub];
                *(half8*)(zw + wxb * ZS + 8 * wsub) = e8;
            } else if (wsub == 2) {
                zw[wxb * ZS + 16] = xo4[t * 4 + wxb];
            }
        }

        __syncthreads();

        // heads: 24 dot-products x 16 lanes each (8 strided FMAs + shfl reduce)
        if (tid < 384) {
            const int grp = tid >> 4;       // 0..23, wave-aligned 16-thread groups
            const int l16 = tid & 15;
            const int b   = grp & 3, o = grp >> 2;  // o = 0..5
            float s = 0.0f;
            #pragma unroll
            for (int j = 0; j < 8; ++j) {
                const int k = l16 + 16 * j;
                s += wh_lds[o * Hc + k] * h32_lds[b * 132 + k];
            }
            s += __shfl_xor(s, 1);
            s += __shfl_xor(s, 2);
            s += __shfl_xor(s, 4);
            s += __shfl_xor(s, 8);
            if (l16 == 0) {
                const int gb = b0 + b;
                if (o == 0) {
                    const float mu = s + bm0;
                    out[gb * DECc + t] = mu;
                    zw[b * ZS + (INc - 1)] = (_Float16)mu;   // mu feedback into x slot 17
                } else if (o == 1) {
                    out[65536 + gb * DECc + t] = softplus_(s + bs0);
                } else {
                    out[131072 + (gb * DECc + t) * 4 + (o - 2)] = s + hb_lds[2 + (o - 2)];
                }
            }
        }
        __syncthreads();
        p ^= 1;
    }
    #undef LOAD_T
}

extern "C" void kernel_launch(void* const* d_in, const int* in_sizes, int n_in,
                              void* d_out, int out_size, void* d_ws, size_t ws_size,
                              hipStream_t stream) {
    rnnar_kernel<<<1024 / NBc, NTc, 0, stream>>>(
        (const int*)d_in[0],   (const float*)d_in[1],  (const float*)d_in[2],
        (const int*)d_in[3],   (const float*)d_in[4],  (const float*)d_in[5],
        (const float*)d_in[6],
        (const float*)d_in[7], (const float*)d_in[8],  (const float*)d_in[9],
        (const float*)d_in[10],(const float*)d_in[11], (const float*)d_in[12],
        (const float*)d_in[13],(const float*)d_in[14],
        (const float*)d_in[15],(const float*)d_in[16],
        (const float*)d_in[17],(const float*)d_in[18],
        (float*)d_out);
}

// Round 7
// 1151.652 us; speedup vs baseline: 1.2169x; 1.1015x over previous
//
#include <hip/hip_runtime.h>
#include <math.h>

typedef _Float16 half8 __attribute__((ext_vector_type(8)));
typedef float float4v __attribute__((ext_vector_type(4)));

constexpr int Lc   = 2048;  // L_IN
constexpr int DECc = 64;    // DEC_LEN
constexpr int Hc   = 128;   // H
constexpr int EMBc = 16;    // EMB
constexpr int INc  = 18;    // IN_SIZE
constexpr int NBc  = 4;     // batches per block
constexpr int NTc  = 512;   // 8 waves
constexpr int KT   = 5;     // k-tiles of 32 (z padded to 160)
constexpr int CARD = 200;
constexpr int ZS   = 160;   // z stride per batch (halves); 320B -> 2-way (free) on b128 reads

// Empirically best configuration (Round 1, 1150 us wall / 1211 us steady).
// R2-R6 each improved an individual counter (bank conflicts, x-gather, writer
// straggle) but regressed end-to-end by 100-250 us: the targeted terms are
// ~5-20 cy/step while the collateral scheduling/spill cost of each edit was
// ~100+ cy/step. This is the verbatim R1 kernel.
//
// Structure: z = [x(18) | h(128) | pad] double-buffered in LDS; 5 uniform
// k-tiles of 32; gate-type-per-accumulator MFMA layout so all four gates of
// one (cell,batch) land in-lane (no LDS gate shuffle); 72-thread x-writer
// stages x(t+1) into the write buffer; decoder mu feedback through z slot 17.

__device__ __forceinline__ float rcp_(float x) { return __builtin_amdgcn_rcpf(x); }
__device__ __forceinline__ float sigm(float x) { return rcp_(1.0f + __expf(-x)); }
__device__ __forceinline__ float tanh_(float x) { return 2.0f * rcp_(1.0f + __expf(-2.0f * x)) - 1.0f; }
__device__ __forceinline__ float softplus_(float x) { return __logf(1.0f + __expf(x)); }

// dynamic 4-element select (3 cndmask) -- replaces the LDS gate shuffle
__device__ __forceinline__ float sel4(float4v v, int q) {
    const float a = (q & 1) ? v[1] : v[0];
    const float b = (q & 1) ? v[3] : v[2];
    return (q & 2) ? b : a;
}

// Gate-type-per-accumulator layout (no shuffle):
//   wave wv owns cells 16wv..16wv+15; acc[gt] computes gates of type gt for those cells.
// A-frag (z): lane holds A[m=col][k=quad*8+j], A[m] = z[batch m&3]  (batches replicated)
// B-frag:     lane holds B[k=kt*32+quad*8+j][n=col], B[k][n] = W[gt*128 + 16wv+col][k]
// C: col = cell-local, reg r = batch (rows are batch mod 4) -> lane (q,col) keeps batch q:
//    acc[0..3][q] = i,f,g,o of (cell=16wv+col, batch=q), all in registers.

__global__ __launch_bounds__(NTc, 1) void rnnar_kernel(
    const int*   __restrict__ cat_in,  const float* __restrict__ cont_in,
    const float* __restrict__ X_in,    const int*   __restrict__ cat_out,
    const float* __restrict__ cont_out,const float* __restrict__ emb_table,
    const float* __restrict__ cont_w,
    const float* __restrict__ Wih_e, const float* __restrict__ Whh_e, const float* __restrict__ b_e,
    const float* __restrict__ Wih_d, const float* __restrict__ Whh_d, const float* __restrict__ b_d,
    const float* __restrict__ Wm, const float* __restrict__ bm,
    const float* __restrict__ Ws, const float* __restrict__ bs,
    const float* __restrict__ Wv, const float* __restrict__ bv,
    float* __restrict__ out)
{
    __shared__ _Float16      z_lds[2][NBc * ZS];   // 2.5 KB double-buffered z, [b][k]
    __shared__ _Float16      emb_lds[CARD * EMBc]; // 6.4 KB
    __shared__ _Float16      xs0[NBc * Lc];        // 16 KB cont_in * w00
    __shared__ _Float16      xs1[NBc * Lc];        // 16 KB X_in
    __shared__ _Float16      xo_lds[NBc * DECc];   // 512 B cont_out * w00
    __shared__ unsigned char catb[NBc * Lc];       // 8 KB
    __shared__ unsigned char catob[NBc * DECc];    // 256 B
    __shared__ float         h32_lds[NBc * 132];   // 2.1 KB
    __shared__ float         wh_lds[6 * Hc];       // 3 KB
    __shared__ float         hb_lds[8];

    const int tid  = threadIdx.x;
    const int lane = tid & 63;
    const int wv   = tid >> 6;        // wave 0..7
    const int q    = lane >> 4;       // quad 0..3 = this lane's batch
    const int col  = lane & 15;       // cell-local 0..15
    const int cell = 16 * wv + col;   // this lane's cell
    const int bx   = col & 3;         // A-frag batch
    const int b0   = blockIdx.x * NBc;
    const float w00 = cont_w[0];

    const int xk = tid >> 2, xb = tid & 3;   // x-writer role (tid < 72)

    // ---------------- staging ----------------
    {
        int* z32 = (int*)&z_lds[0][0];
        for (int i = tid; i < NBc * ZS; i += NTc) z32[i] = 0;  // both buffers
    }
    for (int i = tid; i < NBc * Lc; i += NTc) {
        const int b = i >> 11, t = i & (Lc - 1);
        catb[i] = (unsigned char)cat_in[(b0 + b) * Lc + t];
        xs0[i]  = (_Float16)(cont_in[(b0 + b) * Lc + t] * w00);
        xs1[i]  = (_Float16)(X_in[(b0 + b) * Lc + t]);
    }
    if (tid < NBc * DECc) {
        const int b = tid >> 6, t = tid & 63;
        catob[tid]  = (unsigned char)cat_out[(b0 + b) * DECc + t];
        xo_lds[tid] = (_Float16)(cont_out[(b0 + b) * DECc + t] * w00);
    }
    for (int i = tid; i < CARD * EMBc; i += NTc) emb_lds[i] = (_Float16)emb_table[i];
    for (int i = tid; i < 6 * Hc; i += NTc) {
        const int o = i >> 7, k = i & 127;
        wh_lds[i] = (o == 0) ? Wm[k] : (o == 1) ? Ws[k] : Wv[(o - 2) * Hc + k];
    }
    if (tid == 0) { hb_lds[0] = bm[0]; hb_lds[1] = bs[0]; }
    if (tid < 4)  { hb_lds[2 + tid] = bv[tid]; }

    // ---- B-fragments: acc tile index == gate type; row = gt*128 + cell ----
    half8 Bf[4][KT];
    float bias_s[4];
    #define LOAD_T(WIH, WHH, BB)                                               \
    {                                                                          \
        _Pragma("unroll")                                                      \
        for (int gt = 0; gt < 4; ++gt) {                                       \
            const int row = gt * Hc + cell;                                    \
            _Pragma("unroll")                                                  \
            for (int kt = 0; kt < KT; ++kt) {                                  \
                half8 f;                                                       \
                _Pragma("unroll")                                              \
                for (int j = 0; j < 8; ++j) {                                  \
                    const int k = 32 * kt + 8 * q + j;                         \
                    float v = 0.0f;                                            \
                    if (k < INc)            v = WIH[row * INc + k];            \
                    else if (k < INc + Hc)  v = WHH[row * Hc + (k - INc)];     \
                    f[j] = (_Float16)v;                                        \
                }                                                              \
                Bf[gt][kt] = f;                                                \
            }                                                                  \
            bias_s[gt] = BB[row];                                              \
        }                                                                      \
    }

    LOAD_T(Wih_e, Whh_e, b_e);
    __syncthreads();

    // x(0) into buffer 0
    if (tid < INc * NBc) {
        _Float16 v;
        if (xk < EMBc)       v = emb_lds[(int)catb[xb * Lc] * EMBc + xk];
        else if (xk == EMBc) v = xs0[xb * Lc];
        else                 v = xs1[xb * Lc];
        z_lds[0][xb * ZS + xk] = v;
    }
    __syncthreads();

    int p = 0;
    float c_reg = 0.f;

    // ===================== encoder: 1 barrier/step, no gate shuffle =====================
    for (int t = 0; t < Lc; ++t) {
        const _Float16* zr = &z_lds[p][0];
        _Float16*       zw = &z_lds[p ^ 1][0];

        // A-frags from z (batch = col&3)
        const _Float16* ap = zr + bx * ZS + 8 * q;
        half8 Az[KT];
        #pragma unroll
        for (int kt = 0; kt < KT; ++kt) Az[kt] = *(const half8*)(ap + 32 * kt);

        float4v acc[4];
        #pragma unroll
        for (int gt = 0; gt < 4; ++gt) {
            float4v a = {bias_s[gt], bias_s[gt], bias_s[gt], bias_s[gt]};
            #pragma unroll
            for (int kt = 0; kt < KT; ++kt)
                a = __builtin_amdgcn_mfma_f32_16x16x32_f16(Az[kt], Bf[gt][kt], a, 0, 0, 0);
            acc[gt] = a;
        }

        // gates land in-lane: batch q, cell = 16wv+col
        const float gi = sel4(acc[0], q);
        const float gf = sel4(acc[1], q);
        const float gg = sel4(acc[2], q);
        const float go = sel4(acc[3], q);

        const float cn = sigm(gf) * c_reg + sigm(gi) * tanh_(gg);
        c_reg = cn;
        zw[q * ZS + INc + cell] = (_Float16)(sigm(go) * tanh_(cn));

        // x(t+1) (clamped: t=Lc-1 writes decoder-init x)
        if (tid < INc * NBc) {
            const int t1 = (t + 1 < Lc) ? t + 1 : Lc - 1;
            _Float16 v;
            if (xk < EMBc)       v = emb_lds[(int)catb[xb * Lc + t1] * EMBc + xk];
            else if (xk == EMBc) v = xs0[xb * Lc + t1];
            else                 v = xs1[xb * Lc + t1];
            zw[xb * ZS + xk] = v;
        }
        __syncthreads();
        p ^= 1;
    }

    // ===================== decoder =====================
    LOAD_T(Wih_d, Whh_d, b_d);
    const float bm0 = hb_lds[0], bs0 = hb_lds[1];

    for (int t = 0; t < DECc; ++t) {
        const _Float16* zr = &z_lds[p][0];
        _Float16*       zw = &z_lds[p ^ 1][0];

        const _Float16* ap = zr + bx * ZS + 8 * q;
        half8 Az[KT];
        #pragma unroll
        for (int kt = 0; kt < KT; ++kt) Az[kt] = *(const half8*)(ap + 32 * kt);

        float4v acc[4];
        #pragma unroll
        for (int gt = 0; gt < 4; ++gt) {
            float4v a = {bias_s[gt], bias_s[gt], bias_s[gt], bias_s[gt]};
            #pragma unroll
            for (int kt = 0; kt < KT; ++kt)
                a = __builtin_amdgcn_mfma_f32_16x16x32_f16(Az[kt], Bf[gt][kt], a, 0, 0, 0);
            acc[gt] = a;
        }

        const float gi = sel4(acc[0], q);
        const float gf = sel4(acc[1], q);
        const float gg = sel4(acc[2], q);
        const float go = sel4(acc[3], q);

        const float cn = sigm(gf) * c_reg + sigm(gi) * tanh_(gg);
        c_reg = cn;
        const float hv = sigm(go) * tanh_(cn);
        zw[q * ZS + INc + cell] = (_Float16)hv;
        h32_lds[q * 132 + cell] = hv;

        // feats_out(t) -> x(t+1); slot 17 (mu) written by heads
        if (tid < INc * NBc && xk < INc - 1) {
            _Float16 v;
            if (xk < EMBc) v = emb_lds[(int)catob[xb * DECc + t] * EMBc + xk];
            else           v = xo_lds[xb * DECc + t];
            zw[xb * ZS + xk] = v;
        }
        __syncthreads();

        // heads: 24 dot-products x 16 lanes each (8 strided FMAs + shfl reduce)
        if (tid < 384) {
            const int grp = tid >> 4;       // 0..23, 16-thread groups (wave-aligned)
            const int l16 = tid & 15;
            const int b   = grp & 3, o = grp >> 2;  // o = 0..5
            float s = 0.0f;
            #pragma unroll
            for (int j = 0; j < 8; ++j) {
                const int k = l16 + 16 * j;
                s += wh_lds[o * Hc + k] * h32_lds[b * 132 + k];
            }
            s += __shfl_xor(s, 1);
            s += __shfl_xor(s, 2);
            s += __shfl_xor(s, 4);
            s += __shfl_xor(s, 8);
            if (l16 == 0) {
                const int gb = b0 + b;
                if (o == 0) {
                    const float mu = s + bm0;
                    out[gb * DECc + t] = mu;
                    zw[b * ZS + (INc - 1)] = (_Float16)mu;   // mu feedback
                } else if (o == 1) {
                    out[65536 + gb * DECc + t] = softplus_(s + bs0);
                } else {
                    out[131072 + (gb * DECc + t) * 4 + (o - 2)] = s + hb_lds[2 + (o - 2)];
                }
            }
        }
        __syncthreads();
        p ^= 1;
    }
    #undef LOAD_T
}

extern "C" void kernel_launch(void* const* d_in, const int* in_sizes, int n_in,
                              void* d_out, int out_size, void* d_ws, size_t ws_size,
                              hipStream_t stream) {
    rnnar_kernel<<<1024 / NBc, NTc, 0, stream>>>(
        (const int*)d_in[0],   (const float*)d_in[1],  (const float*)d_in[2],
        (const int*)d_in[3],   (const float*)d_in[4],  (const float*)d_in[5],
        (const float*)d_in[6],
        (const float*)d_in[7], (const float*)d_in[8],  (const float*)d_in[9],
        (const float*)d_in[10],(const float*)d_in[11], (const float*)d_in[12],
        (const float*)d_in[13],(const float*)d_in[14],
        (const float*)d_in[15],(const float*)d_in[16],
        (const float*)d_in[17],(const float*)d_in[18],
        (float*)d_out);
}